// Round 8
// baseline (128.448 us; speedup 1.0000x reference)
//
#include <hip/hip_runtime.h>

// SiamFC cross-correlation: out[n,0,oh,ow] = sum_{c,i,j} x[n,c,oh+i,ow+j] * z[n,c,i,j]
// n=256, c=256, z=6x6, x=26x26, out=21x21.
//
// Round-8: one block per sample (grid=256, 512 thr = 8 waves/CU). 16 rounds x
// 16 channels, double-buffered LDS fed by global_load_lds(16B); every wave
// issues exactly 7 loads/round -> s_waitcnt vmcnt(7) + raw s_barrier (loads for
// round r+1 fly under round r's FMAs). Lanes: cc=tid&15 (channel), g=(tid>>4)&1
// (col half), t=(tid>>5)&7 (3-row tile, 7 used), h=tid>>8 (z rows 3h..3h+2).
// Per thread/round: 594 FMA per 49 ds_read_b64; linear LDS (gload_lds needs it),
// worst bank aliasing 2-way = free (m136). Epilogue: shfl_xor over cc (lane
// bits 0-3), LDS fold over h, direct stores. No memset, no atomics.

#define XBUF_F 10816            // 16 ch * 676 floats
#define ZBUF_F 576              // 16 ch * 36 floats
#define BUFSTRIDE 11392         // floats, 16B multiple
#define NTHREADS 512
#define ROUNDS 16
#define SLOT 34                 // h-fold slot stride (33 + 1)

typedef __attribute__((address_space(3))) unsigned int lds_u32_t;
typedef __attribute__((address_space(1))) const unsigned int glb_u32_t;

__device__ __forceinline__ void gload16(const void* g, void* l) {
    __builtin_amdgcn_global_load_lds((glb_u32_t*)g, (lds_u32_t*)l, 16, 0, 0);
}

__global__ __launch_bounds__(NTHREADS, 2)
void siamfc_xcorr(const float* __restrict__ z, const float* __restrict__ x,
                  float* __restrict__ out) {
    __shared__ __align__(16) float lds[2 * BUFSTRIDE];   // 91 KB

    const int tid  = threadIdx.x;
    const int lane = tid & 63;
    const int w    = tid >> 6;          // wave 0..7
    const int n    = blockIdx.x;

    const int cc = tid & 15;            // channel within round
    const int g  = (tid >> 4) & 1;      // col half: cols 10g + o
    const int t  = (tid >> 5) & 7;      // row tile (t=7 idle in compute)
    const int h  = tid >> 8;            // z rows 3h..3h+2
    const bool active = (t < 7);

    const float4* xg4 = (const float4*)x + (size_t)n * (256 * 169);
    const float4* zg4 = (const float4*)z + (size_t)n * (256 * 9);

    // 7 global_load_lds per wave per round (5 strided x + 1 x tail + 1 z)
    auto issue = [&](int r, int b) {
        const float4* xsrc = xg4 + (size_t)(16 * r) * 169;   // 2704 quads
        const float4* zsrc = zg4 + (size_t)(16 * r) * 9;     // 144 quads
        float* xb = lds + b * BUFSTRIDE;
        float* zb = xb + XBUF_F;
        #pragma unroll
        for (int k = 0; k < 5; ++k)      // quads k*512 + tid  (0..2559)
            gload16(xsrc + (k * 512 + tid), xb + (size_t)(k * 512 + w * 64) * 4);
        if (lane < 18) {                 // x quads 2560..2703 (18 per wave)
            gload16(xsrc + (2560 + 18 * w + lane), xb + (size_t)(2560 + 18 * w) * 4);
            // z quads 0..143 (18 per wave)
            gload16(zsrc + (18 * w + lane), zb + (size_t)(18 * w) * 4);
        }
    };

    float acc[33];
    #pragma unroll
    for (int v = 0; v < 33; ++v) acc[v] = 0.f;

    issue(0, 0);

    #pragma unroll 1
    for (int r = 0; r < ROUNDS; ++r) {
        if (r + 1 < ROUNDS) {
            issue(r + 1, (r + 1) & 1);
            asm volatile("s_waitcnt vmcnt(7)" ::: "memory");  // round-r loads done
        } else {
            asm volatile("s_waitcnt vmcnt(0)" ::: "memory");
        }
        __builtin_amdgcn_s_barrier();
        asm volatile("" ::: "memory");

        if (active) {
            const float* xb = lds + (r & 1) * BUFSTRIDE;
            const float* zb = xb + XBUF_F;
            // z rows 3h..3h+2 of channel cc: 9 float2 (2-way aliased broadcasts)
            float zv[3][6];
            const float2* zp = (const float2*)(zb + cc * 36 + h * 18);
            #pragma unroll
            for (int e = 0; e < 9; ++e) {
                float2 q = zp[e];
                zv[e / 3][2 * (e % 3)]     = q.x;
                zv[e / 3][2 * (e % 3) + 1] = q.y;
            }
            const float2* xcb = (const float2*)xb + 338 * cc + 5 * g;
            #pragma unroll
            for (int m = 0; m < 5; ++m) {               // x rows 3t+3h+m (<=25)
                const int row = 3 * t + 3 * h + m;
                const float2* rp = xcb + 13 * row;
                float xr[16];                           // row floats 10g..10g+15
                #pragma unroll
                for (int s = 0; s < 8; ++s) {
                    float2 q = rp[s];
                    xr[2 * s] = q.x; xr[2 * s + 1] = q.y;
                }
                #pragma unroll
                for (int zr = 0; zr < 3; ++zr) {
                    const int a = m - zr;               // output row 3t+a
                    if (a >= 0 && a < 3) {
                        #pragma unroll
                        for (int j = 0; j < 6; ++j)
                            #pragma unroll
                            for (int o = 0; o < 11; ++o)   // out col 10g+o
                                acc[a * 11 + o] = fmaf(zv[zr][j], xr[o + j], acc[a * 11 + o]);
                    }
                }
            }
        }
        __builtin_amdgcn_s_barrier();
        asm volatile("" ::: "memory");
    }

    // ---- reduce over cc (lane bits 0..3): 4 shfl_xor steps
    #pragma unroll
    for (int v = 0; v < 33; ++v) {
        acc[v] += __shfl_xor(acc[v], 1, 64);
        acc[v] += __shfl_xor(acc[v], 2, 64);
        acc[v] += __shfl_xor(acc[v], 4, 64);
        acc[v] += __shfl_xor(acc[v], 8, 64);
    }
    // ---- fold h via LDS (loop-end barrier already passed; lds reusable)
    if (active && cc == 0 && h == 1) {
        float* sl = lds + (size_t)(t * 2 + g) * SLOT;
        #pragma unroll
        for (int v = 0; v < 33; ++v) sl[v] = acc[v];
    }
    __syncthreads();
    if (active && cc == 0 && h == 0) {
        const float* sl = lds + (size_t)(t * 2 + g) * SLOT;
        float* og = out + (size_t)n * (21 * 21);
        #pragma unroll
        for (int a = 0; a < 3; ++a) {
            const int row = 3 * t + a;
            for (int o = g; o < 11; ++o) {        // g=1 skips o=0 (col-10 dup)
                const int col = 10 * g + o;
                og[row * 21 + col] = acc[a * 11 + o] + sl[a * 11 + o];
            }
        }
    }
}

extern "C" void kernel_launch(void* const* d_in, const int* in_sizes, int n_in,
                              void* d_out, int out_size, void* d_ws, size_t ws_size,
                              hipStream_t stream) {
    const float* z = (const float*)d_in[0];
    const float* x = (const float*)d_in[1];
    float* out = (float*)d_out;
    siamfc_xcorr<<<dim3(256), dim3(NTHREADS), 0, stream>>>(z, x, out);
}

// Round 9
// 59.551 us; speedup vs baseline: 2.1570x; 2.1570x over previous
//
#include <hip/hip_runtime.h>

// SiamFC cross-correlation: out[n,0,oh,ow] = sum_{c,i,j} x[n,c,oh+i,ow+j] * z[n,c,i,j]
// n=256, c=256, z=6x6, x=26x26, out=21x21.
//
// Round-9 = Round-7 geometry (the proven winner: 2048 blocks, 128 thr, 22.8 KB
// LDS -> 7 blocks/CU; global_load_lds(16B) double-buffered with counted
// s_waitcnt vmcnt(7) + raw s_barrier) with the epilogue de-serialized:
//   - no hipMemsetAsync in the graph
//   - no atomics: each (n,split) block plain-stores 441 partials to d_ws
//   - second tiny kernel folds the 8 splits -> d_out (coalesced).

#define HX 26
#define WX 26
#define OH 21
#define OW 21
#define XBUF 2704              // 4 ch * 676 floats
#define ZBUF 144               // 4 ch * 36 floats
#define BUFSTRIDE 2848         // XBUF + ZBUF (floats, 16B multiple)
#define NTHREADS 128
#define ROUNDS 8
#define SPLITS 8
#define SLOT 36                // partial slot stride (floats)
#define WS_STRIDE 448          // per-(split,n) ws slot (floats)

typedef __attribute__((address_space(3))) unsigned int lds_u32_t;
typedef __attribute__((address_space(1))) const unsigned int glb_u32_t;

__device__ __forceinline__ void gload16(const void* g, void* l) {
    __builtin_amdgcn_global_load_lds((glb_u32_t*)g, (lds_u32_t*)l, 16, 0, 0);
}

__global__ __launch_bounds__(NTHREADS, 3)
void siamfc_xcorr_part(const float* __restrict__ z, const float* __restrict__ x,
                       float* __restrict__ ws) {
    __shared__ __align__(16) float lds[2 * BUFSTRIDE];

    const int tid  = threadIdx.x;
    const int lane = tid & 63;
    const int w    = tid >> 6;          // wave id == h
    const int bid  = blockIdx.x;
    const int n     = bid >> 3;
    const int split = bid & 7;
    const int cb0   = split * 32;       // 32 channels per block

    const int cc = tid & 3;
    const int g  = (tid >> 2) & 1;      // col half: cols 10g + o
    const int t  = (tid >> 3) & 7;      // 0..7, t==7 idle in compute
    const int h  = w;
    const bool active = (t < 7);

    const float4* xg4 = (const float4*)x + (size_t)n * (256 * 169);
    const float4* zg4 = (const float4*)z + (size_t)n * (256 * 9);

    // issue the 7 per-wave global_load_lds for round r into buffer b
    auto issue = [&](int r, int b) {
        const float4* xsrc = xg4 + (size_t)(cb0 + 4 * r) * 169;  // 676 quads
        const float4* zsrc = zg4 + (size_t)(cb0 + 4 * r) * 9;    // 36 quads
        float* xb = lds + b * BUFSTRIDE;
        float* zb = xb + XBUF;
        #pragma unroll
        for (int k = 0; k < 5; ++k)                      // quads k*128 + tid
            gload16(xsrc + k * 128 + tid, xb + (size_t)(k * 128 + w * 64) * 4);
        if (lane < 18) {                                 // x quads 640..675
            gload16(xsrc + 640 + w * 18 + lane, xb + (size_t)(640 + w * 18) * 4);
            // z quads 0..35
            gload16(zsrc + w * 18 + lane, zb + (size_t)(w * 18) * 4);
        }
    };

    float acc[33];
    #pragma unroll
    for (int v = 0; v < 33; ++v) acc[v] = 0.f;

    issue(0, 0);

    #pragma unroll 1
    for (int r = 0; r < ROUNDS; ++r) {
        if (r < ROUNDS - 1) {
            issue(r + 1, (r + 1) & 1);
            asm volatile("s_waitcnt vmcnt(7)" ::: "memory");  // round-r loads done
        } else {
            asm volatile("s_waitcnt vmcnt(0)" ::: "memory");
        }
        __builtin_amdgcn_s_barrier();
        asm volatile("" ::: "memory");

        if (active) {
            const float* xb = lds + (r & 1) * BUFSTRIDE;
            const float* zb = xb + XBUF;
            // z rows 3h..3h+2 of channel cc: 9 float2 broadcasts
            float zv[3][6];
            const float2* zp = (const float2*)(zb + cc * 36 + h * 18);
            #pragma unroll
            for (int e = 0; e < 9; ++e) {
                float2 q = zp[e];
                zv[e / 3][2 * (e % 3)]     = q.x;
                zv[e / 3][2 * (e % 3) + 1] = q.y;
            }
            const float* xcb = xb + cc * 676;
            #pragma unroll
            for (int m = 0; m < 5; ++m) {                // x rows 3t+3h+m
                const int row = 3 * t + 3 * h + m;       // <= 25
                const float2* rp = (const float2*)xcb + 13 * row + 5 * g;
                float xr[16];                            // row floats 10g..10g+15
                #pragma unroll
                for (int s = 0; s < 8; ++s) {
                    float2 q = rp[s];
                    xr[2 * s] = q.x; xr[2 * s + 1] = q.y;
                }
                #pragma unroll
                for (int zr = 0; zr < 3; ++zr) {
                    const int a = m - zr;                // output row 3t+a
                    if (a >= 0 && a < 3) {
                        #pragma unroll
                        for (int j = 0; j < 6; ++j)
                            #pragma unroll
                            for (int o = 0; o < 11; ++o) // out col 10g+o
                                acc[a * 11 + o] = fmaf(zv[zr][j], xr[o + j], acc[a * 11 + o]);
                    }
                }
            }
        }
        __builtin_amdgcn_s_barrier();
        asm volatile("" ::: "memory");
    }

    // ---- reduce: shfl_xor across cc (lane bits 0,1), LDS slots across h
    #pragma unroll
    for (int v = 0; v < 33; ++v) {
        acc[v] += __shfl_xor(acc[v], 1, 64);
        acc[v] += __shfl_xor(acc[v], 2, 64);
    }
    if (active && cc == 0) {
        float* wsl = lds + (size_t)(h * 14 + t * 2 + g) * SLOT;
        #pragma unroll
        for (int v = 0; v < 33; ++v) wsl[v] = acc[v];
    }
    __syncthreads();

    // ---- plain store of this split's 441 partials (no atomics, no memset)
    float* wp = ws + (size_t)(split * 256 + n) * WS_STRIDE;
    for (int o = tid; o < OH * OW; o += NTHREADS) {
        int row = o / OW, c = o - row * OW;
        int tt = row / 3, a = row - tt * 3;
        int gg = (c >= 11) ? 1 : 0;
        int vi = a * 11 + (c - 10 * gg);
        wp[o] = lds[(      tt * 2 + gg) * SLOT + vi]
              + lds[(14 +  tt * 2 + gg) * SLOT + vi];
    }
}

__global__ __launch_bounds__(WS_STRIDE, 4)
void siamfc_reduce(const float* __restrict__ ws, float* __restrict__ out) {
    const int n = blockIdx.x;
    const int o = threadIdx.x;
    if (o >= OH * OW) return;
    float s = 0.f;
    #pragma unroll
    for (int sp = 0; sp < SPLITS; ++sp)
        s += ws[(size_t)(sp * 256 + n) * WS_STRIDE + o];
    out[(size_t)n * (OH * OW) + o] = s;
}

extern "C" void kernel_launch(void* const* d_in, const int* in_sizes, int n_in,
                              void* d_out, int out_size, void* d_ws, size_t ws_size,
                              hipStream_t stream) {
    const float* z = (const float*)d_in[0];
    const float* x = (const float*)d_in[1];
    float* out = (float*)d_out;
    float* ws  = (float*)d_ws;
    siamfc_xcorr_part<<<dim3(256 * SPLITS), dim3(NTHREADS), 0, stream>>>(z, x, ws);
    siamfc_reduce<<<dim3(256), dim3(WS_STRIDE), 0, stream>>>(ws, out);
}